// Round 1
// baseline (705.424 us; speedup 1.0000x reference)
//
#include <hip/hip_runtime.h>
#include <math.h>

#define B_    512
#define N_    32
#define H_    128
#define KRANK 3
#define PSTEPS 10
#define TSTEPS 100

// ---------------- K0: transpose W1 [h][k] -> W1t [k][h] ----------------
__global__ void k0_transpose(const float* __restrict__ W1, float* __restrict__ W1t) {
    int tid = blockIdx.x * 256 + threadIdx.x;
    if (tid < H_ * H_) {
        int h = tid / H_, k = tid % H_;
        W1t[k * H_ + h] = W1[h * H_ + k];
    }
}

// ---------------- K1: per-edge MLP, raw (pre-symmetrize) outputs ----------------
// out[...,k] = sum_h e[...,h] * W1[h,k]  -> relu -> @W2 + b2 (b2 added here, summed twice by symmetrize)
__global__ __launch_bounds__(256) void k1_mlp(
    const float* __restrict__ e, const float* __restrict__ W1t,
    const float* __restrict__ b1, const float* __restrict__ W2,
    const float* __restrict__ b2,
    float* __restrict__ r0, float* __restrict__ r1) {
    long edge = (long)blockIdx.x * 256 + threadIdx.x;   // 524288 edges
    const float* ep = e + edge * H_;
    float er[H_];
    #pragma unroll
    for (int k = 0; k < H_; k += 4) {
        float4 v = *(const float4*)(ep + k);
        er[k] = v.x; er[k+1] = v.y; er[k+2] = v.z; er[k+3] = v.w;
    }
    float o0 = b2[0], o1 = b2[1];
    for (int j = 0; j < H_; j++) {
        float acc = b1[j];
        const float* wrow = W1t + j * H_;      // uniform address -> s_load
        #pragma unroll
        for (int k = 0; k < H_; k++) acc = fmaf(er[k], wrow[k], acc);
        float h = fmaxf(acc, 0.f);
        o0 = fmaf(h, W2[2*j],   o0);
        o1 = fmaf(h, W2[2*j+1], o1);
    }
    r0[edge] = o0;
    r1[edge] = o1;
}

// ---------------- K2: symmetrize + softplus, in place over pairs (i<=j) ----------------
__device__ __forceinline__ float softplusf(float x) {
    return x > 20.f ? x : log1pf(expf(x));
}

__global__ void k2_sym(float* __restrict__ r0, float* __restrict__ r1) {
    int t = blockIdx.x * 256 + threadIdx.x;    // 512 * 528 = 270336 pairs
    int b = t / 528, r = t % 528;
    // triangular index: i such that r >= i*(65-i)/2 ; 4225-8r = (65-2i)^2 at row starts (exact in f32)
    float disc = sqrtf((float)(4225 - 8 * r));
    int i = (int)((65.f - disc) * 0.5f);
    int j = r - (i * (65 - i)) / 2 + i;
    int base = b * 1024;
    int ij = base + i * 32 + j;
    int ji = base + j * 32 + i;
    float s0 = r0[ij] + r0[ji];
    float s1 = r1[ij] + r1[ji];
    float Dv = (i == j) ? 0.f : softplusf(s0);   // mask = 1 - eye
    float Wv = softplusf(s1);
    r0[ij] = Dv; r0[ji] = Dv;
    r1[ij] = Wv; r1[ji] = Wv;
}

// ---------------- K3: per-batch Gram + power iteration + 100 GD steps ----------------
__global__ __launch_bounds__(128) void k3_solve(
    const float* __restrict__ Dg, const float* __restrict__ Wg,
    const float* __restrict__ noise, const float* __restrict__ u_init,
    float* __restrict__ Xout) {
    int b = blockIdx.x;
    int tid = threadIdx.x;

    __shared__ float Ds[32][33];
    __shared__ float Ws_[32][33];
    __shared__ float Gs[32][33];
    __shared__ float Xs[32][4];
    __shared__ float cs[32][33];
    __shared__ float dxs[32][4];

    const float* Db = Dg + b * 1024;
    const float* Wb = Wg + b * 1024;
    for (int idx = tid; idx < 1024; idx += 128) {
        int i = idx >> 5, j = idx & 31;
        Ds[i][j]  = Db[idx];
        Ws_[i][j] = Wb[idx];
    }
    __syncthreads();

    // G = D^T D : G[i][j] = sum_k D[k][i] * D[k][j]
    for (int idx = tid; idx < 1024; idx += 128) {
        int i = idx >> 5, j = idx & 31;
        float acc = 0.f;
        #pragma unroll
        for (int k = 0; k < 32; k++) acc = fmaf(Ds[k][i], Ds[k][j], acc);
        Gs[i][j] = acc;
    }
    __syncthreads();

    // rank-3 deflated power iteration on lanes 0..31 of wave 0 (register A, shfl broadcasts)
    if (tid < 32) {
        int lane = tid;
        float Arow[32];
        #pragma unroll
        for (int j = 0; j < 32; j++) Arow[j] = Gs[lane][j];
        float x0 = 0.f, x1 = 0.f, x2 = 0.f;
        for (int s = 0; s < KRANK; s++) {
            float u = u_init[((long)s * B_ + b) * 32 + lane];
            for (int p = 0; p < PSTEPS; p++) {
                float red = u * u;
                #pragma unroll
                for (int m = 1; m < 32; m <<= 1) red += __shfl_xor(red, m, 32);
                float nrm = fmaxf(sqrtf(red), 1e-3f);
                float un = u / nrm;
                float acc = 0.f;
                #pragma unroll
                for (int j = 0; j < 32; j++) acc = fmaf(Arow[j], __shfl(un, j, 32), acc);
                u = acc;
            }
            float red = u * u;
            #pragma unroll
            for (int m = 1; m < 32; m <<= 1) red += __shfl_xor(red, m, 32);
            float sc = sqrtf(sqrtf(red + 0.01f));      // (eig_sq + 0.01)^0.25
            u *= sc;
            if (s == 0) x0 = u; else if (s == 1) x1 = u; else x2 = u;
            #pragma unroll
            for (int j = 0; j < 32; j++) Arow[j] = fmaf(-u, __shfl(u, j, 32), Arow[j]);
        }
        const float* nb = noise + ((long)b * 32 + lane) * 3;
        Xs[lane][0] = x0 + nb[0];
        Xs[lane][1] = x1 + nb[1];
        Xs[lane][2] = x2 + nb[2];
    }
    __syncthreads();

    // 100 gradient-descent steps with tanh trust region
    for (int t = 0; t < TSTEPS; t++) {
        float a_t = 0.1f + 4.9f * (float)(TSTEPS - t) / (float)TSTEPS;
        // phase A: pair coefficients c_ij = -4 W (D - DX) / DX
        for (int p = tid; p < 1024; p += 128) {
            int i = p >> 5, j = p & 31;
            float dx = Xs[i][0] - Xs[j][0];
            float dy = Xs[i][1] - Xs[j][1];
            float dz = Xs[i][2] - Xs[j][2];
            float DX = sqrtf(fmaf(dx, dx, fmaf(dy, dy, fmaf(dz, dz, 0.01f))));
            cs[i][j] = -4.f * Ws_[i][j] * (Ds[i][j] - DX) / DX;
        }
        __syncthreads();
        // phase B: grad_id = xi * sum_j c_ij - sum_j c_ij * x_jd ; dX = -LR*grad
        if (tid < 96) {
            int i = tid / 3, d = tid % 3;
            float xi = Xs[i][d];
            float sc_ = 0.f, scx = 0.f;
            #pragma unroll
            for (int j = 0; j < 32; j++) {
                float cv = cs[i][j];
                sc_ += cv;
                scx = fmaf(cv, Xs[j][d], scx);
            }
            float g = fmaf(xi, sc_, -scx);
            dxs[i][d] = -0.1f * g;
        }
        __syncthreads();
        // phase C: trust-region scale + update
        if (tid < 96) {
            int i = tid / 3, d = tid % 3;
            float d0 = dxs[i][0], d1 = dxs[i][1], d2v = dxs[i][2];
            float speed = sqrtf(fmaf(d0, d0, fmaf(d1, d1, fmaf(d2v, d2v, 1e-3f))));
            float sc2 = a_t * tanhf(speed / a_t) / speed;
            Xs[i][d] = fmaf(dxs[i][d], sc2, Xs[i][d]);
        }
        __syncthreads();
    }

    if (tid < 96) {
        int i = tid / 3, d = tid % 3;
        Xout[((long)b * 32 + i) * 3 + d] = Xs[i][d];
    }
}

extern "C" void kernel_launch(void* const* d_in, const int* in_sizes, int n_in,
                              void* d_out, int out_size, void* d_ws, size_t ws_size,
                              hipStream_t stream) {
    const float* e      = (const float*)d_in[0];
    const float* W1     = (const float*)d_in[1];
    const float* b1     = (const float*)d_in[2];
    const float* W2     = (const float*)d_in[3];
    const float* b2     = (const float*)d_in[4];
    const float* noise  = (const float*)d_in[5];
    const float* u_init = (const float*)d_in[6];
    float* out = (float*)d_out;

    float* W1t = (float*)d_ws;   // 64 KB

    float* r0 = out;             // D region, used first as raw ch0
    float* r1 = out + 524288;    // W region, used first as raw ch1
    float* X  = out + 1048576;   // X_pred region

    hipLaunchKernelGGL(k0_transpose, dim3(64),   dim3(256), 0, stream, W1, W1t);
    hipLaunchKernelGGL(k1_mlp,       dim3(2048), dim3(256), 0, stream, e, W1t, b1, W2, b2, r0, r1);
    hipLaunchKernelGGL(k2_sym,       dim3(1056), dim3(256), 0, stream, r0, r1);
    hipLaunchKernelGGL(k3_solve,     dim3(512),  dim3(128), 0, stream, r0, r1, noise, u_init, X);
}

// Round 2
// 509.872 us; speedup vs baseline: 1.3835x; 1.3835x over previous
//
#include <hip/hip_runtime.h>
#include <math.h>

#define B_    512
#define N_    32
#define H_    128
#define KRANK 3
#define PSTEPS 10
#define TSTEPS 100

// ---------------- K1: per-edge MLP, raw (pre-symmetrize) outputs ----------------
// Loop order: stream e 4-at-a-time, hold all 128 hidden accumulators in VGPRs.
// W1 rows are wave-uniform -> scalar loads (no transpose needed).
__global__ __launch_bounds__(256) void k1_mlp(
    const float* __restrict__ e, const float* __restrict__ W1,
    const float* __restrict__ b1, const float* __restrict__ W2,
    const float* __restrict__ b2,
    float* __restrict__ r0, float* __restrict__ r1) {
    long edge = (long)blockIdx.x * 256 + threadIdx.x;   // 524288 edges
    const float* ep = e + edge * H_;

    float hacc[H_];
    #pragma unroll
    for (int j = 0; j < H_; ++j) hacc[j] = b1[j];

    #pragma unroll 1
    for (int h = 0; h < H_; h += 4) {
        float4 ev = *(const float4*)(ep + h);
        const float* w = W1 + (long)h * H_;
        #pragma unroll
        for (int j = 0; j < H_; ++j) {
            float a = hacc[j];
            a = fmaf(ev.x, w[j],        a);
            a = fmaf(ev.y, w[j + H_],   a);
            a = fmaf(ev.z, w[j + 2*H_], a);
            a = fmaf(ev.w, w[j + 3*H_], a);
            hacc[j] = a;
        }
    }

    float o0 = b2[0], o1 = b2[1];
    #pragma unroll
    for (int j = 0; j < H_; ++j) {
        float hv = fmaxf(hacc[j], 0.f);
        o0 = fmaf(hv, W2[2*j],   o0);
        o1 = fmaf(hv, W2[2*j+1], o1);
    }
    r0[edge] = o0;
    r1[edge] = o1;
}

// ---------------- K2: symmetrize + softplus, in place over pairs (i<=j) ----------------
__device__ __forceinline__ float softplusf(float x) {
    return x > 20.f ? x : log1pf(expf(x));
}

__global__ void k2_sym(float* __restrict__ r0, float* __restrict__ r1) {
    int t = blockIdx.x * 256 + threadIdx.x;    // 512 * 528 = 270336 pairs
    int b = t / 528, r = t % 528;
    float disc = sqrtf((float)(4225 - 8 * r));
    int i = (int)((65.f - disc) * 0.5f);
    int j = r - (i * (65 - i)) / 2 + i;
    int base = b * 1024;
    int ij = base + i * 32 + j;
    int ji = base + j * 32 + i;
    float s0 = r0[ij] + r0[ji];
    float s1 = r1[ij] + r1[ji];
    float Dv = (i == j) ? 0.f : softplusf(s0);
    float Wv = softplusf(s1);
    r0[ij] = Dv; r0[ji] = Dv;
    r1[ij] = Wv; r1[ji] = Wv;
}

// ---------------- K3: one wave64 per batch, wave-synchronous (no s_barrier) ----------------
__global__ __launch_bounds__(64) void k3_solve(
    const float* __restrict__ Dg, const float* __restrict__ Wg,
    const float* __restrict__ noise, const float* __restrict__ u_init,
    float* __restrict__ Xout) {
    int b = blockIdx.x;
    int l = threadIdx.x;            // 0..63

    __shared__ float Ds[32][33];
    __shared__ float Ws_[32][33];
    __shared__ float Gs[32][33];
    __shared__ float Xs[32][5];     // stride 5 (coprime with 32): conflict-free column reads

    const float* Db = Dg + b * 1024;
    const float* Wb = Wg + b * 1024;
    #pragma unroll 1
    for (int s = 0; s < 16; ++s) {
        int idx = s * 64 + l;
        int i = idx >> 5, j = idx & 31;
        Ds[i][j]  = Db[idx];
        Ws_[i][j] = Wb[idx];
    }
    __builtin_amdgcn_wave_barrier();

    // G = D^T D
    #pragma unroll 1
    for (int s = 0; s < 16; ++s) {
        int idx = s * 64 + l;
        int i = idx >> 5, j = idx & 31;
        float acc = 0.f;
        #pragma unroll
        for (int k = 0; k < 32; ++k) acc = fmaf(Ds[k][i], Ds[k][j], acc);
        Gs[i][j] = acc;
    }
    __builtin_amdgcn_wave_barrier();

    // rank-3 deflated power iteration on lanes 0..31 (register A, shfl broadcasts)
    if (l < 32) {
        float Arow[32];
        #pragma unroll
        for (int j = 0; j < 32; ++j) Arow[j] = Gs[l][j];
        float x0 = 0.f, x1 = 0.f, x2 = 0.f;
        for (int s = 0; s < KRANK; ++s) {
            float u = u_init[((long)s * B_ + b) * 32 + l];
            for (int p = 0; p < PSTEPS; ++p) {
                float red = u * u;
                #pragma unroll
                for (int m = 1; m < 32; m <<= 1) red += __shfl_xor(red, m, 32);
                float un = u / fmaxf(sqrtf(red), 1e-3f);
                float acc = 0.f;
                #pragma unroll
                for (int j = 0; j < 32; ++j) acc = fmaf(Arow[j], __shfl(un, j, 32), acc);
                u = acc;
            }
            float red = u * u;
            #pragma unroll
            for (int m = 1; m < 32; m <<= 1) red += __shfl_xor(red, m, 32);
            float sc = sqrtf(sqrtf(red + 0.01f));      // (eig_sq + 0.01)^0.25
            u *= sc;
            if (s == 0) x0 = u; else if (s == 1) x1 = u; else x2 = u;
            #pragma unroll
            for (int j = 0; j < 32; ++j) Arow[j] = fmaf(-u, __shfl(u, j, 32), Arow[j]);
        }
        const float* nb = noise + ((long)b * 32 + l) * 3;
        Xs[l][0] = x0 + nb[0];
        Xs[l][1] = x1 + nb[1];
        Xs[l][2] = x2 + nb[2];
    }
    __builtin_amdgcn_wave_barrier();

    // cache my D/W half-row in registers (constant across GD steps)
    int i = l & 31, half = l >> 5;   // lane handles atom i, j-range [half*16, half*16+16)
    float Drow[16], Wrow[16];
    #pragma unroll
    for (int jj = 0; jj < 16; ++jj) {
        int j = half * 16 + jj;
        Drow[jj] = Ds[i][j];
        Wrow[jj] = Ws_[i][j];
    }

    // 100 gradient-descent steps with tanh trust region, fully wave-synchronous
    #pragma unroll 1
    for (int t = 0; t < TSTEPS; ++t) {
        float a_t = 0.1f + 4.9f * (float)(TSTEPS - t) / (float)TSTEPS;
        float xi0 = Xs[i][0], xi1 = Xs[i][1], xi2 = Xs[i][2];
        float sc_ = 0.f, s0 = 0.f, s1 = 0.f, s2 = 0.f;
        #pragma unroll
        for (int jj = 0; jj < 16; ++jj) {
            int j = half * 16 + jj;
            float xj0 = Xs[j][0], xj1 = Xs[j][1], xj2 = Xs[j][2];
            float dx = xi0 - xj0, dy = xi1 - xj1, dz = xi2 - xj2;
            float DX = sqrtf(fmaf(dx, dx, fmaf(dy, dy, fmaf(dz, dz, 0.01f))));
            float c = -4.f * Wrow[jj] * (Drow[jj] - DX) / DX;
            sc_ += c;
            s0 = fmaf(c, xj0, s0);
            s1 = fmaf(c, xj1, s1);
            s2 = fmaf(c, xj2, s2);
        }
        // combine the two half-wave partial sums
        sc_ += __shfl_xor(sc_, 32);
        s0  += __shfl_xor(s0, 32);
        s1  += __shfl_xor(s1, 32);
        s2  += __shfl_xor(s2, 32);
        float g0 = fmaf(xi0, sc_, -s0);
        float g1 = fmaf(xi1, sc_, -s1);
        float g2 = fmaf(xi2, sc_, -s2);
        float d0 = -0.1f * g0, d1 = -0.1f * g1, d2 = -0.1f * g2;
        float speed = sqrtf(fmaf(d0, d0, fmaf(d1, d1, fmaf(d2, d2, 1e-3f))));
        float sc2 = a_t * tanhf(speed / a_t) / speed;
        __builtin_amdgcn_wave_barrier();   // all Xs reads precede writes (in-order DS pipe)
        if (l < 32) {
            Xs[i][0] = fmaf(d0, sc2, xi0);
            Xs[i][1] = fmaf(d1, sc2, xi1);
            Xs[i][2] = fmaf(d2, sc2, xi2);
        }
        __builtin_amdgcn_wave_barrier();
    }

    if (l < 32) {
        float* xo = Xout + ((long)b * 32 + i) * 3;
        xo[0] = Xs[i][0];
        xo[1] = Xs[i][1];
        xo[2] = Xs[i][2];
    }
}

extern "C" void kernel_launch(void* const* d_in, const int* in_sizes, int n_in,
                              void* d_out, int out_size, void* d_ws, size_t ws_size,
                              hipStream_t stream) {
    const float* e      = (const float*)d_in[0];
    const float* W1     = (const float*)d_in[1];
    const float* b1     = (const float*)d_in[2];
    const float* W2     = (const float*)d_in[3];
    const float* b2     = (const float*)d_in[4];
    const float* noise  = (const float*)d_in[5];
    const float* u_init = (const float*)d_in[6];
    float* out = (float*)d_out;

    float* r0 = out;             // D region, used first as raw ch0
    float* r1 = out + 524288;    // W region, used first as raw ch1
    float* X  = out + 1048576;   // X_pred region

    hipLaunchKernelGGL(k1_mlp,   dim3(2048), dim3(256), 0, stream, e, W1, b1, W2, b2, r0, r1);
    hipLaunchKernelGGL(k2_sym,   dim3(1056), dim3(256), 0, stream, r0, r1);
    hipLaunchKernelGGL(k3_solve, dim3(512),  dim3(64),  0, stream, r0, r1, noise, u_init, X);
}

// Round 3
// 509.386 us; speedup vs baseline: 1.3848x; 1.0010x over previous
//
#include <hip/hip_runtime.h>
#include <math.h>

#define B_    512
#define N_    32
#define H_    128
#define KRANK 3
#define PSTEPS 10
#define TSTEPS 100

// 128-instance list macro: forces 128 NAMED scalar accumulators (no alloca -> no scratch demotion)
#define LIST128(M) \
  M(0) M(1) M(2) M(3) M(4) M(5) M(6) M(7) \
  M(8) M(9) M(10) M(11) M(12) M(13) M(14) M(15) \
  M(16) M(17) M(18) M(19) M(20) M(21) M(22) M(23) \
  M(24) M(25) M(26) M(27) M(28) M(29) M(30) M(31) \
  M(32) M(33) M(34) M(35) M(36) M(37) M(38) M(39) \
  M(40) M(41) M(42) M(43) M(44) M(45) M(46) M(47) \
  M(48) M(49) M(50) M(51) M(52) M(53) M(54) M(55) \
  M(56) M(57) M(58) M(59) M(60) M(61) M(62) M(63) \
  M(64) M(65) M(66) M(67) M(68) M(69) M(70) M(71) \
  M(72) M(73) M(74) M(75) M(76) M(77) M(78) M(79) \
  M(80) M(81) M(82) M(83) M(84) M(85) M(86) M(87) \
  M(88) M(89) M(90) M(91) M(92) M(93) M(94) M(95) \
  M(96) M(97) M(98) M(99) M(100) M(101) M(102) M(103) \
  M(104) M(105) M(106) M(107) M(108) M(109) M(110) M(111) \
  M(112) M(113) M(114) M(115) M(116) M(117) M(118) M(119) \
  M(120) M(121) M(122) M(123) M(124) M(125) M(126) M(127)

// ---------------- K1: per-edge MLP, raw (pre-symmetrize) outputs ----------------
// 128 named scalar hidden accumulators in VGPRs; e streamed as float4;
// W1 rows wave-uniform -> scalar loads.
__global__ __launch_bounds__(256) void k1_mlp(
    const float* __restrict__ e, const float* __restrict__ W1,
    const float* __restrict__ b1, const float* __restrict__ W2,
    const float* __restrict__ b2,
    float* __restrict__ r0, float* __restrict__ r1) {
    long edge = (long)blockIdx.x * 256 + threadIdx.x;   // 524288 edges
    const float* ep = e + edge * H_;

#define DECL_H(n) float h##n = b1[n];
    LIST128(DECL_H)
#undef DECL_H

    #pragma unroll 1
    for (int h = 0; h < H_; h += 4) {
        float4 ev = *(const float4*)(ep + h);
        const float* w = W1 + (long)h * H_;
#define FMA_H(n) \
        h##n = fmaf(ev.x, w[(n)],        h##n); \
        h##n = fmaf(ev.y, w[(n) + 128],  h##n); \
        h##n = fmaf(ev.z, w[(n) + 256],  h##n); \
        h##n = fmaf(ev.w, w[(n) + 384],  h##n);
        LIST128(FMA_H)
#undef FMA_H
    }

    float o0 = b2[0], o1 = b2[1];
#define OUT_H(n) { float hv = fmaxf(h##n, 0.f); \
        o0 = fmaf(hv, W2[2*(n)],     o0); \
        o1 = fmaf(hv, W2[2*(n) + 1], o1); }
    LIST128(OUT_H)
#undef OUT_H

    r0[edge] = o0;
    r1[edge] = o1;
}

// ---------------- K2: symmetrize + softplus, in place over pairs (i<=j) ----------------
__device__ __forceinline__ float softplusf(float x) {
    return x > 20.f ? x : log1pf(expf(x));
}

__global__ void k2_sym(float* __restrict__ r0, float* __restrict__ r1) {
    int t = blockIdx.x * 256 + threadIdx.x;    // 512 * 528 = 270336 pairs
    int b = t / 528, r = t % 528;
    float disc = sqrtf((float)(4225 - 8 * r));
    int i = (int)((65.f - disc) * 0.5f);
    int j = r - (i * (65 - i)) / 2 + i;
    int base = b * 1024;
    int ij = base + i * 32 + j;
    int ji = base + j * 32 + i;
    float s0 = r0[ij] + r0[ji];
    float s1 = r1[ij] + r1[ji];
    float Dv = (i == j) ? 0.f : softplusf(s0);
    float Wv = softplusf(s1);
    r0[ij] = Dv; r0[ji] = Dv;
    r1[ij] = Wv; r1[ji] = Wv;
}

// ---------------- K3: one wave64 per batch, wave-synchronous (no s_barrier) ----------------
__global__ __launch_bounds__(64) void k3_solve(
    const float* __restrict__ Dg, const float* __restrict__ Wg,
    const float* __restrict__ noise, const float* __restrict__ u_init,
    float* __restrict__ Xout) {
    int b = blockIdx.x;
    int l = threadIdx.x;            // 0..63

    __shared__ float Ds[32][33];
    __shared__ float Ws_[32][33];
    __shared__ float Gs[32][33];
    __shared__ float Xs[32][5];

    const float* Db = Dg + b * 1024;
    const float* Wb = Wg + b * 1024;
    #pragma unroll 1
    for (int s = 0; s < 16; ++s) {
        int idx = s * 64 + l;
        int i = idx >> 5, j = idx & 31;
        Ds[i][j]  = Db[idx];
        Ws_[i][j] = Wb[idx];
    }
    __builtin_amdgcn_wave_barrier();

    // G = D^T D
    #pragma unroll 1
    for (int s = 0; s < 16; ++s) {
        int idx = s * 64 + l;
        int i = idx >> 5, j = idx & 31;
        float acc = 0.f;
        #pragma unroll
        for (int k = 0; k < 32; ++k) acc = fmaf(Ds[k][i], Ds[k][j], acc);
        Gs[i][j] = acc;
    }
    __builtin_amdgcn_wave_barrier();

    // rank-3 deflated power iteration on lanes 0..31 (register A, shfl broadcasts)
    if (l < 32) {
        float Arow[32];
        #pragma unroll
        for (int j = 0; j < 32; ++j) Arow[j] = Gs[l][j];
        float x0 = 0.f, x1 = 0.f, x2 = 0.f;
        for (int s = 0; s < KRANK; ++s) {
            float u = u_init[((long)s * B_ + b) * 32 + l];
            for (int p = 0; p < PSTEPS; ++p) {
                float red = u * u;
                #pragma unroll
                for (int m = 1; m < 32; m <<= 1) red += __shfl_xor(red, m, 32);
                float un = u / fmaxf(sqrtf(red), 1e-3f);
                float acc = 0.f;
                #pragma unroll
                for (int j = 0; j < 32; ++j) acc = fmaf(Arow[j], __shfl(un, j, 32), acc);
                u = acc;
            }
            float red = u * u;
            #pragma unroll
            for (int m = 1; m < 32; m <<= 1) red += __shfl_xor(red, m, 32);
            float sc = sqrtf(sqrtf(red + 0.01f));      // (eig_sq + 0.01)^0.25
            u *= sc;
            if (s == 0) x0 = u; else if (s == 1) x1 = u; else x2 = u;
            #pragma unroll
            for (int j = 0; j < 32; ++j) Arow[j] = fmaf(-u, __shfl(u, j, 32), Arow[j]);
        }
        const float* nb = noise + ((long)b * 32 + l) * 3;
        Xs[l][0] = x0 + nb[0];
        Xs[l][1] = x1 + nb[1];
        Xs[l][2] = x2 + nb[2];
    }
    __builtin_amdgcn_wave_barrier();

    // cache my D/W half-row in registers (constant across GD steps)
    int i = l & 31, half = l >> 5;
    float Drow[16], Wrow[16];
    #pragma unroll
    for (int jj = 0; jj < 16; ++jj) {
        int j = half * 16 + jj;
        Drow[jj] = Ds[i][j];
        Wrow[jj] = Ws_[i][j];
    }

    // 100 gradient-descent steps with tanh trust region, fully wave-synchronous
    #pragma unroll 1
    for (int t = 0; t < TSTEPS; ++t) {
        float a_t = 0.1f + 4.9f * (float)(TSTEPS - t) / (float)TSTEPS;
        float xi0 = Xs[i][0], xi1 = Xs[i][1], xi2 = Xs[i][2];
        float sc_ = 0.f, s0 = 0.f, s1 = 0.f, s2 = 0.f;
        #pragma unroll
        for (int jj = 0; jj < 16; ++jj) {
            int j = half * 16 + jj;
            float xj0 = Xs[j][0], xj1 = Xs[j][1], xj2 = Xs[j][2];
            float dx = xi0 - xj0, dy = xi1 - xj1, dz = xi2 - xj2;
            float DX = sqrtf(fmaf(dx, dx, fmaf(dy, dy, fmaf(dz, dz, 0.01f))));
            float c = -4.f * Wrow[jj] * (Drow[jj] - DX) / DX;
            sc_ += c;
            s0 = fmaf(c, xj0, s0);
            s1 = fmaf(c, xj1, s1);
            s2 = fmaf(c, xj2, s2);
        }
        sc_ += __shfl_xor(sc_, 32);
        s0  += __shfl_xor(s0, 32);
        s1  += __shfl_xor(s1, 32);
        s2  += __shfl_xor(s2, 32);
        float g0 = fmaf(xi0, sc_, -s0);
        float g1 = fmaf(xi1, sc_, -s1);
        float g2 = fmaf(xi2, sc_, -s2);
        float d0 = -0.1f * g0, d1 = -0.1f * g1, d2 = -0.1f * g2;
        float speed = sqrtf(fmaf(d0, d0, fmaf(d1, d1, fmaf(d2, d2, 1e-3f))));
        float sc2 = a_t * tanhf(speed / a_t) / speed;
        __builtin_amdgcn_wave_barrier();
        if (l < 32) {
            Xs[i][0] = fmaf(d0, sc2, xi0);
            Xs[i][1] = fmaf(d1, sc2, xi1);
            Xs[i][2] = fmaf(d2, sc2, xi2);
        }
        __builtin_amdgcn_wave_barrier();
    }

    if (l < 32) {
        float* xo = Xout + ((long)b * 32 + i) * 3;
        xo[0] = Xs[i][0];
        xo[1] = Xs[i][1];
        xo[2] = Xs[i][2];
    }
}

extern "C" void kernel_launch(void* const* d_in, const int* in_sizes, int n_in,
                              void* d_out, int out_size, void* d_ws, size_t ws_size,
                              hipStream_t stream) {
    const float* e      = (const float*)d_in[0];
    const float* W1     = (const float*)d_in[1];
    const float* b1     = (const float*)d_in[2];
    const float* W2     = (const float*)d_in[3];
    const float* b2     = (const float*)d_in[4];
    const float* noise  = (const float*)d_in[5];
    const float* u_init = (const float*)d_in[6];
    float* out = (float*)d_out;

    float* r0 = out;             // D region, used first as raw ch0
    float* r1 = out + 524288;    // W region, used first as raw ch1
    float* X  = out + 1048576;   // X_pred region

    hipLaunchKernelGGL(k1_mlp,   dim3(2048), dim3(256), 0, stream, e, W1, b1, W2, b2, r0, r1);
    hipLaunchKernelGGL(k2_sym,   dim3(1056), dim3(256), 0, stream, r0, r1);
    hipLaunchKernelGGL(k3_solve, dim3(512),  dim3(64),  0, stream, r0, r1, noise, u_init, X);
}

// Round 4
// 318.012 us; speedup vs baseline: 2.2182x; 1.6018x over previous
//
#include <hip/hip_runtime.h>
#include <math.h>

#define B_    512
#define N_    32
#define H_    128
#define KRANK 3
#define PSTEPS 10
#define TSTEPS 100

typedef __attribute__((ext_vector_type(4))) float f32x4;
typedef __attribute__((ext_vector_type(8))) short bf16x8;
typedef __attribute__((ext_vector_type(4))) unsigned short u16x4;

__device__ __forceinline__ unsigned short bf16_rne(float x) {
    unsigned int u = __float_as_uint(x);
    u += 0x7FFFu + ((u >> 16) & 1u);
    return (unsigned short)(u >> 16);
}

// ---------------- kprep: pack W1 hi/lo into per-lane MFMA B-fragment order ----------------
// Wpk[bk][nf][lane][i] : bk 0..3 = hi blocks (k = bk*32 + (lane>>4)*8 + i),
//                        bk 4..7 = lo blocks (k = (bk-4)*32 + ...)
// value = B[k][n] with n = nf*16 + (lane&15)
__global__ void kprep_w(const float* __restrict__ W1, unsigned short* __restrict__ Wpk) {
    int t = blockIdx.x * 256 + threadIdx.x;   // 4096 threads
    int lane = t & 63, nf = (t >> 6) & 7, bk = t >> 9;
    int n = nf * 16 + (lane & 15);
    int kbase = (bk & 3) * 32 + (lane >> 4) * 8;
    u16x4 o0, o1;
    #pragma unroll
    for (int i = 0; i < 8; ++i) {
        float w = W1[(kbase + i) * H_ + n];
        unsigned short hi = bf16_rne(w);
        unsigned short v;
        if (bk < 4) v = hi;
        else        v = bf16_rne(w - __uint_as_float((unsigned int)hi << 16));
        if (i < 4) o0[i] = v; else o1[i - 4] = v;
    }
    u16x4* dst = (u16x4*)(Wpk + (long)t * 8);
    dst[0] = o0;
    dst[1] = o1;
}

// ---------------- K1: fused 2-layer MLP via split-bf16 MFMA ----------------
// Per block: 64 edges, 128 threads (2 waves), wave tile = 32 edges x 128 hidden.
// K=384 logical: (e_hi,w_hi), (e_lo,w_hi), (e_hi,w_lo). Layer 2 in f32 on VALU.
#define PADJ 136
__global__ __launch_bounds__(128, 1) void k1_mlp(
    const float* __restrict__ e, const unsigned short* __restrict__ Wpk,
    const float* __restrict__ b1, const float* __restrict__ W2,
    const float* __restrict__ b2,
    float* __restrict__ r0, float* __restrict__ r1) {

    __shared__ __attribute__((aligned(16))) unsigned short Ahi[64 * PADJ];
    __shared__ __attribute__((aligned(16))) unsigned short Alo[64 * PADJ];

    int tid = threadIdx.x;
    long ebase = (long)blockIdx.x * 64;

    // stage + hi/lo split of the 64x128 e-tile
    #pragma unroll
    for (int it = 0; it < 16; ++it) {
        int flat = it * 128 + tid;
        int row = flat >> 5, col4 = flat & 31;
        f32x4 v = *(const f32x4*)(e + (ebase + row) * H_ + col4 * 4);
        u16x4 hi4, lo4;
        #pragma unroll
        for (int q = 0; q < 4; ++q) {
            unsigned short h = bf16_rne(v[q]);
            hi4[q] = h;
            lo4[q] = bf16_rne(v[q] - __uint_as_float((unsigned int)h << 16));
        }
        *(u16x4*)&Ahi[row * PADJ + col4 * 4] = hi4;
        *(u16x4*)&Alo[row * PADJ + col4 * 4] = lo4;
    }
    __syncthreads();

    int lane = tid & 63, wv = tid >> 6;
    int mrow = lane & 15, khalf = lane >> 4;

    float b1v[8];
    #pragma unroll
    for (int nf = 0; nf < 8; ++nf) b1v[nf] = b1[nf * 16 + mrow];

    f32x4 acc[2][8];
    #pragma unroll
    for (int mf = 0; mf < 2; ++mf)
        #pragma unroll
        for (int nf = 0; nf < 8; ++nf)
            acc[mf][nf] = (f32x4){b1v[nf], b1v[nf], b1v[nf], b1v[nf]};

    #pragma unroll 2
    for (int kk = 0; kk < 12; ++kk) {
        const unsigned short* ab = (kk >= 4 && kk < 8) ? Alo : Ahi;
        int kin = (kk & 3) * 32 + khalf * 8;
        int bk  = (kk < 4) ? kk : kk - 4;
        bf16x8 bfr[8];
        #pragma unroll
        for (int nf = 0; nf < 8; ++nf)
            bfr[nf] = *(const bf16x8*)(Wpk + (((bk * 8 + nf) * 64 + lane) * 8));
        #pragma unroll
        for (int mf = 0; mf < 2; ++mf) {
            bf16x8 av = *(const bf16x8*)&ab[(wv * 32 + mf * 16 + mrow) * PADJ + kin];
            #pragma unroll
            for (int nf = 0; nf < 8; ++nf)
                acc[mf][nf] = __builtin_amdgcn_mfma_f32_16x16x32_bf16(
                    av, bfr[nf], acc[mf][nf], 0, 0, 0);
        }
    }

    // layer 2: o_c = sum_j relu(h_j) * W2[j,c], f32 on VALU + 16-lane reduce
    float w2a[8], w2b[8];
    #pragma unroll
    for (int nf = 0; nf < 8; ++nf) {
        int j = nf * 16 + mrow;
        w2a[nf] = W2[j * 2];
        w2b[nf] = W2[j * 2 + 1];
    }
    float bb0 = b2[0], bb1 = b2[1];
    #pragma unroll
    for (int mf = 0; mf < 2; ++mf) {
        #pragma unroll
        for (int r = 0; r < 4; ++r) {
            float p0 = 0.f, p1 = 0.f;
            #pragma unroll
            for (int nf = 0; nf < 8; ++nf) {
                float hv = fmaxf(acc[mf][nf][r], 0.f);
                p0 = fmaf(hv, w2a[nf], p0);
                p1 = fmaf(hv, w2b[nf], p1);
            }
            #pragma unroll
            for (int d = 1; d < 16; d <<= 1) {
                p0 += __shfl_xor(p0, d);
                p1 += __shfl_xor(p1, d);
            }
            if (mrow == 0) {
                long edge = ebase + wv * 32 + mf * 16 + khalf * 4 + r;
                r0[edge] = p0 + bb0;
                r1[edge] = p1 + bb1;
            }
        }
    }
}

// ---------------- K2: symmetrize + softplus, in place over pairs (i<=j) ----------------
__device__ __forceinline__ float softplusf(float x) {
    return x > 20.f ? x : log1pf(expf(x));
}

__global__ void k2_sym(float* __restrict__ r0, float* __restrict__ r1) {
    int t = blockIdx.x * 256 + threadIdx.x;    // 512 * 528 = 270336 pairs
    int b = t / 528, r = t % 528;
    float disc = sqrtf((float)(4225 - 8 * r));
    int i = (int)((65.f - disc) * 0.5f);
    int j = r - (i * (65 - i)) / 2 + i;
    int base = b * 1024;
    int ij = base + i * 32 + j;
    int ji = base + j * 32 + i;
    float s0 = r0[ij] + r0[ji];
    float s1 = r1[ij] + r1[ji];
    float Dv = (i == j) ? 0.f : softplusf(s0);
    float Wv = softplusf(s1);
    r0[ij] = Dv; r0[ji] = Dv;
    r1[ij] = Wv; r1[ji] = Wv;
}

// ---------------- K3: one wave64 per batch, wave-synchronous (no s_barrier) ----------------
__global__ __launch_bounds__(64) void k3_solve(
    const float* __restrict__ Dg, const float* __restrict__ Wg,
    const float* __restrict__ noise, const float* __restrict__ u_init,
    float* __restrict__ Xout) {
    int b = blockIdx.x;
    int l = threadIdx.x;            // 0..63

    __shared__ float Ds[32][33];
    __shared__ float Ws_[32][33];
    __shared__ float Gs[32][33];
    __shared__ float Xs[32][5];

    const float* Db = Dg + b * 1024;
    const float* Wb = Wg + b * 1024;
    #pragma unroll 1
    for (int s = 0; s < 16; ++s) {
        int idx = s * 64 + l;
        int i = idx >> 5, j = idx & 31;
        Ds[i][j]  = Db[idx];
        Ws_[i][j] = Wb[idx];
    }
    __builtin_amdgcn_wave_barrier();

    // G = D^T D
    #pragma unroll 1
    for (int s = 0; s < 16; ++s) {
        int idx = s * 64 + l;
        int i = idx >> 5, j = idx & 31;
        float acc = 0.f;
        #pragma unroll
        for (int k = 0; k < 32; ++k) acc = fmaf(Ds[k][i], Ds[k][j], acc);
        Gs[i][j] = acc;
    }
    __builtin_amdgcn_wave_barrier();

    // rank-3 deflated power iteration on lanes 0..31 (register A, shfl broadcasts)
    if (l < 32) {
        float Arow[32];
        #pragma unroll
        for (int j = 0; j < 32; ++j) Arow[j] = Gs[l][j];
        float x0 = 0.f, x1 = 0.f, x2 = 0.f;
        for (int s = 0; s < KRANK; ++s) {
            float u = u_init[((long)s * B_ + b) * 32 + l];
            for (int p = 0; p < PSTEPS; ++p) {
                float red = u * u;
                #pragma unroll
                for (int m = 1; m < 32; m <<= 1) red += __shfl_xor(red, m, 32);
                float un = u / fmaxf(sqrtf(red), 1e-3f);
                float acc = 0.f;
                #pragma unroll
                for (int j = 0; j < 32; ++j) acc = fmaf(Arow[j], __shfl(un, j, 32), acc);
                u = acc;
            }
            float red = u * u;
            #pragma unroll
            for (int m = 1; m < 32; m <<= 1) red += __shfl_xor(red, m, 32);
            float sc = sqrtf(sqrtf(red + 0.01f));      // (eig_sq + 0.01)^0.25
            u *= sc;
            if (s == 0) x0 = u; else if (s == 1) x1 = u; else x2 = u;
            #pragma unroll
            for (int j = 0; j < 32; ++j) Arow[j] = fmaf(-u, __shfl(u, j, 32), Arow[j]);
        }
        const float* nb = noise + ((long)b * 32 + l) * 3;
        Xs[l][0] = x0 + nb[0];
        Xs[l][1] = x1 + nb[1];
        Xs[l][2] = x2 + nb[2];
    }
    __builtin_amdgcn_wave_barrier();

    // cache my D/W half-row in registers (constant across GD steps)
    int i = l & 31, half = l >> 5;
    float Drow[16], Wrow[16];
    #pragma unroll
    for (int jj = 0; jj < 16; ++jj) {
        int j = half * 16 + jj;
        Drow[jj] = Ds[i][j];
        Wrow[jj] = Ws_[i][j];
    }

    // 100 gradient-descent steps with tanh trust region, fully wave-synchronous
    #pragma unroll 1
    for (int t = 0; t < TSTEPS; ++t) {
        float a_t = 0.1f + 4.9f * (float)(TSTEPS - t) / (float)TSTEPS;
        float xi0 = Xs[i][0], xi1 = Xs[i][1], xi2 = Xs[i][2];
        float sc_ = 0.f, s0 = 0.f, s1 = 0.f, s2 = 0.f;
        #pragma unroll
        for (int jj = 0; jj < 16; ++jj) {
            int j = half * 16 + jj;
            float xj0 = Xs[j][0], xj1 = Xs[j][1], xj2 = Xs[j][2];
            float dx = xi0 - xj0, dy = xi1 - xj1, dz = xi2 - xj2;
            float DX = sqrtf(fmaf(dx, dx, fmaf(dy, dy, fmaf(dz, dz, 0.01f))));
            float c = -4.f * Wrow[jj] * (Drow[jj] - DX) / DX;
            sc_ += c;
            s0 = fmaf(c, xj0, s0);
            s1 = fmaf(c, xj1, s1);
            s2 = fmaf(c, xj2, s2);
        }
        sc_ += __shfl_xor(sc_, 32);
        s0  += __shfl_xor(s0, 32);
        s1  += __shfl_xor(s1, 32);
        s2  += __shfl_xor(s2, 32);
        float g0 = fmaf(xi0, sc_, -s0);
        float g1 = fmaf(xi1, sc_, -s1);
        float g2 = fmaf(xi2, sc_, -s2);
        float d0 = -0.1f * g0, d1 = -0.1f * g1, d2 = -0.1f * g2;
        float speed = sqrtf(fmaf(d0, d0, fmaf(d1, d1, fmaf(d2, d2, 1e-3f))));
        float sc2 = a_t * tanhf(speed / a_t) / speed;
        __builtin_amdgcn_wave_barrier();
        if (l < 32) {
            Xs[i][0] = fmaf(d0, sc2, xi0);
            Xs[i][1] = fmaf(d1, sc2, xi1);
            Xs[i][2] = fmaf(d2, sc2, xi2);
        }
        __builtin_amdgcn_wave_barrier();
    }

    if (l < 32) {
        float* xo = Xout + ((long)b * 32 + i) * 3;
        xo[0] = Xs[i][0];
        xo[1] = Xs[i][1];
        xo[2] = Xs[i][2];
    }
}

extern "C" void kernel_launch(void* const* d_in, const int* in_sizes, int n_in,
                              void* d_out, int out_size, void* d_ws, size_t ws_size,
                              hipStream_t stream) {
    const float* e      = (const float*)d_in[0];
    const float* W1     = (const float*)d_in[1];
    const float* b1     = (const float*)d_in[2];
    const float* W2     = (const float*)d_in[3];
    const float* b2     = (const float*)d_in[4];
    const float* noise  = (const float*)d_in[5];
    const float* u_init = (const float*)d_in[6];
    float* out = (float*)d_out;

    unsigned short* Wpk = (unsigned short*)d_ws;   // 64 KB packed W1 hi/lo fragments

    float* r0 = out;             // D region, used first as raw ch0
    float* r1 = out + 524288;    // W region, used first as raw ch1
    float* X  = out + 1048576;   // X_pred region

    hipLaunchKernelGGL(kprep_w, dim3(16),   dim3(256), 0, stream, W1, Wpk);
    hipLaunchKernelGGL(k1_mlp,  dim3(8192), dim3(128), 0, stream, e, Wpk, b1, W2, b2, r0, r1);
    hipLaunchKernelGGL(k2_sym,  dim3(1056), dim3(256), 0, stream, r0, r1);
    hipLaunchKernelGGL(k3_solve, dim3(512), dim3(64),  0, stream, r0, r1, noise, u_init, X);
}

// Round 5
// 212.915 us; speedup vs baseline: 3.3132x; 1.4936x over previous
//
#include <hip/hip_runtime.h>
#include <math.h>

#define B_    512
#define N_    32
#define H_    128
#define KRANK 3
#define PSTEPS 10
#define TSTEPS 100

typedef __attribute__((ext_vector_type(4))) float f32x4;
typedef __attribute__((ext_vector_type(8))) short bf16x8;
typedef __attribute__((ext_vector_type(4))) unsigned short u16x4;

__device__ __forceinline__ unsigned short bf16_rne(float x) {
    unsigned int u = __float_as_uint(x);
    u += 0x7FFFu + ((u >> 16) & 1u);
    return (unsigned short)(u >> 16);
}

// tanh for x >= 0 via hardware exp/rcp: 1 - 2/(e^{2x}+1)
__device__ __forceinline__ float tanh_pos_fast(float x) {
    float e = __expf(2.f * x);
    return 1.f - 2.f * __builtin_amdgcn_rcpf(e + 1.f);
}

// ---------------- kprep: pack W1 hi/lo into per-lane MFMA B-fragment order ----------------
__global__ void kprep_w(const float* __restrict__ W1, unsigned short* __restrict__ Wpk) {
    int t = blockIdx.x * 256 + threadIdx.x;   // 4096 threads
    int lane = t & 63, nf = (t >> 6) & 7, bk = t >> 9;
    int n = nf * 16 + (lane & 15);
    int kbase = (bk & 3) * 32 + (lane >> 4) * 8;
    u16x4 o0, o1;
    #pragma unroll
    for (int i = 0; i < 8; ++i) {
        float w = W1[(kbase + i) * H_ + n];
        unsigned short hi = bf16_rne(w);
        unsigned short v;
        if (bk < 4) v = hi;
        else        v = bf16_rne(w - __uint_as_float((unsigned int)hi << 16));
        if (i < 4) o0[i] = v; else o1[i - 4] = v;
    }
    u16x4* dst = (u16x4*)(Wpk + (long)t * 8);
    dst[0] = o0;
    dst[1] = o1;
}

// ---------------- K1: fused 2-layer MLP via split-bf16 MFMA ----------------
#define PADJ 136
__global__ __launch_bounds__(128, 1) void k1_mlp(
    const float* __restrict__ e, const unsigned short* __restrict__ Wpk,
    const float* __restrict__ b1, const float* __restrict__ W2,
    const float* __restrict__ b2,
    float* __restrict__ r0, float* __restrict__ r1) {

    __shared__ __attribute__((aligned(16))) unsigned short Ahi[64 * PADJ];
    __shared__ __attribute__((aligned(16))) unsigned short Alo[64 * PADJ];

    int tid = threadIdx.x;
    long ebase = (long)blockIdx.x * 64;

    #pragma unroll
    for (int it = 0; it < 16; ++it) {
        int flat = it * 128 + tid;
        int row = flat >> 5, col4 = flat & 31;
        f32x4 v = *(const f32x4*)(e + (ebase + row) * H_ + col4 * 4);
        u16x4 hi4, lo4;
        #pragma unroll
        for (int q = 0; q < 4; ++q) {
            unsigned short h = bf16_rne(v[q]);
            hi4[q] = h;
            lo4[q] = bf16_rne(v[q] - __uint_as_float((unsigned int)h << 16));
        }
        *(u16x4*)&Ahi[row * PADJ + col4 * 4] = hi4;
        *(u16x4*)&Alo[row * PADJ + col4 * 4] = lo4;
    }
    __syncthreads();

    int lane = tid & 63, wv = tid >> 6;
    int mrow = lane & 15, khalf = lane >> 4;

    float b1v[8];
    #pragma unroll
    for (int nf = 0; nf < 8; ++nf) b1v[nf] = b1[nf * 16 + mrow];

    f32x4 acc[2][8];
    #pragma unroll
    for (int mf = 0; mf < 2; ++mf)
        #pragma unroll
        for (int nf = 0; nf < 8; ++nf)
            acc[mf][nf] = (f32x4){b1v[nf], b1v[nf], b1v[nf], b1v[nf]};

    #pragma unroll 2
    for (int kk = 0; kk < 12; ++kk) {
        const unsigned short* ab = (kk >= 4 && kk < 8) ? Alo : Ahi;
        int kin = (kk & 3) * 32 + khalf * 8;
        int bk  = (kk < 4) ? kk : kk - 4;
        bf16x8 bfr[8];
        #pragma unroll
        for (int nf = 0; nf < 8; ++nf)
            bfr[nf] = *(const bf16x8*)(Wpk + (((bk * 8 + nf) * 64 + lane) * 8));
        #pragma unroll
        for (int mf = 0; mf < 2; ++mf) {
            bf16x8 av = *(const bf16x8*)&ab[(wv * 32 + mf * 16 + mrow) * PADJ + kin];
            #pragma unroll
            for (int nf = 0; nf < 8; ++nf)
                acc[mf][nf] = __builtin_amdgcn_mfma_f32_16x16x32_bf16(
                    av, bfr[nf], acc[mf][nf], 0, 0, 0);
        }
    }

    float w2a[8], w2b[8];
    #pragma unroll
    for (int nf = 0; nf < 8; ++nf) {
        int j = nf * 16 + mrow;
        w2a[nf] = W2[j * 2];
        w2b[nf] = W2[j * 2 + 1];
    }
    float bb0 = b2[0], bb1 = b2[1];
    #pragma unroll
    for (int mf = 0; mf < 2; ++mf) {
        #pragma unroll
        for (int r = 0; r < 4; ++r) {
            float p0 = 0.f, p1 = 0.f;
            #pragma unroll
            for (int nf = 0; nf < 8; ++nf) {
                float hv = fmaxf(acc[mf][nf][r], 0.f);
                p0 = fmaf(hv, w2a[nf], p0);
                p1 = fmaf(hv, w2b[nf], p1);
            }
            #pragma unroll
            for (int d = 1; d < 16; d <<= 1) {
                p0 += __shfl_xor(p0, d);
                p1 += __shfl_xor(p1, d);
            }
            if (mrow == 0) {
                long edge = ebase + wv * 32 + mf * 16 + khalf * 4 + r;
                r0[edge] = p0 + bb0;
                r1[edge] = p1 + bb1;
            }
        }
    }
}

// ---------------- K2: symmetrize + softplus, in place over pairs (i<=j) ----------------
__device__ __forceinline__ float softplusf(float x) {
    return x > 20.f ? x : log1pf(expf(x));
}

__global__ void k2_sym(float* __restrict__ r0, float* __restrict__ r1) {
    int t = blockIdx.x * 256 + threadIdx.x;    // 512 * 528 = 270336 pairs
    int b = t / 528, r = t % 528;
    float disc = sqrtf((float)(4225 - 8 * r));
    int i = (int)((65.f - disc) * 0.5f);
    int j = r - (i * (65 - i)) / 2 + i;
    int base = b * 1024;
    int ij = base + i * 32 + j;
    int ji = base + j * 32 + i;
    float s0 = r0[ij] + r0[ji];
    float s1 = r1[ij] + r1[ji];
    float Dv = (i == j) ? 0.f : softplusf(s0);
    float Wv = softplusf(s1);
    r0[ij] = Dv; r0[ji] = Dv;
    r1[ij] = Wv; r1[ji] = Wv;
}

// ---------------- K3: 2 waves per batch, ping-pong X, fast-math chain ----------------
__global__ __launch_bounds__(128) void k3_solve(
    const float* __restrict__ Dg, const float* __restrict__ Wg,
    const float* __restrict__ noise, const float* __restrict__ u_init,
    float* __restrict__ Xout) {
    int b = blockIdx.x;
    int tid = threadIdx.x;          // 0..127

    __shared__ float Ds[32][33];
    __shared__ float Ws_[32][33];
    __shared__ float Gs[32][33];
    __shared__ float Xb[2][32][5];  // ping-pong; stride 5 keeps 4 j-groups on distinct banks

    const float* Db = Dg + b * 1024;
    const float* Wb = Wg + b * 1024;
    #pragma unroll 1
    for (int s = 0; s < 8; ++s) {
        int idx = s * 128 + tid;
        int i = idx >> 5, j = idx & 31;
        Ds[i][j]  = Db[idx];
        Ws_[i][j] = Wb[idx];
    }
    __syncthreads();

    // G = D^T D
    #pragma unroll 1
    for (int s = 0; s < 8; ++s) {
        int idx = s * 128 + tid;
        int i = idx >> 5, j = idx & 31;
        float acc = 0.f;
        #pragma unroll
        for (int k = 0; k < 32; ++k) acc = fmaf(Ds[k][i], Ds[k][j], acc);
        Gs[i][j] = acc;
    }
    __syncthreads();

    // GD-loop lane layout (cache D/W rows while wave 0 runs power iteration)
    int w = tid >> 6, lane = tid & 63;
    int il = lane & 15;             // atom-local index
    int i = w * 16 + il;            // my atom
    int jq = lane >> 4;             // j-quarter 0..3 (8 j's each)
    float Drow[8], Wrow[8];
    #pragma unroll
    for (int jj = 0; jj < 8; ++jj) {
        int j = jq * 8 + jj;
        Drow[jj] = Ds[i][j];
        Wrow[jj] = Ws_[i][j];
    }

    // rank-3 deflated power iteration on lanes 0..31 of wave 0
    if (tid < 32) {
        int l = tid;
        float Arow[32];
        #pragma unroll
        for (int j = 0; j < 32; ++j) Arow[j] = Gs[l][j];
        float x0 = 0.f, x1 = 0.f, x2 = 0.f;
        for (int s = 0; s < KRANK; ++s) {
            float u = u_init[((long)s * B_ + b) * 32 + l];
            for (int p = 0; p < PSTEPS; ++p) {
                float red = u * u;
                #pragma unroll
                for (int m = 1; m < 32; m <<= 1) red += __shfl_xor(red, m, 32);
                float un = u * __builtin_amdgcn_rcpf(fmaxf(__builtin_amdgcn_sqrtf(red), 1e-3f));
                float acc = 0.f;
                #pragma unroll
                for (int j = 0; j < 32; ++j) acc = fmaf(Arow[j], __shfl(un, j, 32), acc);
                u = acc;
            }
            float red = u * u;
            #pragma unroll
            for (int m = 1; m < 32; m <<= 1) red += __shfl_xor(red, m, 32);
            float sc = __builtin_amdgcn_sqrtf(__builtin_amdgcn_sqrtf(red + 0.01f));
            u *= sc;
            if (s == 0) x0 = u; else if (s == 1) x1 = u; else x2 = u;
            #pragma unroll
            for (int j = 0; j < 32; ++j) Arow[j] = fmaf(-u, __shfl(u, j, 32), Arow[j]);
        }
        const float* nb = noise + ((long)b * 32 + l) * 3;
        Xb[0][l][0] = x0 + nb[0];
        Xb[0][l][1] = x1 + nb[1];
        Xb[0][l][2] = x2 + nb[2];
    }
    __syncthreads();

    // 100 GD steps; read Xb[t&1], write Xb[(t&1)^1]; ONE barrier per step
    #pragma unroll 1
    for (int t = 0; t < TSTEPS; ++t) {
        int rb = t & 1;
        float a_t = 0.1f + 4.9f * (float)(TSTEPS - t) / (float)TSTEPS;
        float ra  = __builtin_amdgcn_rcpf(a_t);
        float xi0 = Xb[rb][i][0], xi1 = Xb[rb][i][1], xi2 = Xb[rb][i][2];
        float sc_ = 0.f, s0 = 0.f, s1 = 0.f, s2 = 0.f;
        #pragma unroll
        for (int jj = 0; jj < 8; ++jj) {
            int j = jq * 8 + jj;
            float xj0 = Xb[rb][j][0], xj1 = Xb[rb][j][1], xj2 = Xb[rb][j][2];
            float dx = xi0 - xj0, dy = xi1 - xj1, dz = xi2 - xj2;
            float dd = fmaf(dx, dx, fmaf(dy, dy, fmaf(dz, dz, 0.01f)));
            // c = -4 W (D - DX)/DX = -4 W (D*rsq(dd) - 1)
            float c = -4.f * Wrow[jj] * fmaf(Drow[jj], __builtin_amdgcn_rsqf(dd), -1.f);
            sc_ += c;
            s0 = fmaf(c, xj0, s0);
            s1 = fmaf(c, xj1, s1);
            s2 = fmaf(c, xj2, s2);
        }
        sc_ += __shfl_xor(sc_, 16); s0 += __shfl_xor(s0, 16);
        s1  += __shfl_xor(s1, 16);  s2 += __shfl_xor(s2, 16);
        sc_ += __shfl_xor(sc_, 32); s0 += __shfl_xor(s0, 32);
        s1  += __shfl_xor(s1, 32);  s2 += __shfl_xor(s2, 32);
        if (jq == 0) {
            float d0 = -0.1f * fmaf(xi0, sc_, -s0);
            float d1 = -0.1f * fmaf(xi1, sc_, -s1);
            float d2 = -0.1f * fmaf(xi2, sc_, -s2);
            float sd = fmaf(d0, d0, fmaf(d1, d1, fmaf(d2, d2, 1e-3f)));
            float rs = __builtin_amdgcn_rsqf(sd);          // 1/speed
            float arg = sd * rs * ra;                      // speed/a_t
            float scale = a_t * tanh_pos_fast(arg) * rs;
            Xb[rb ^ 1][i][0] = fmaf(d0, scale, xi0);
            Xb[rb ^ 1][i][1] = fmaf(d1, scale, xi1);
            Xb[rb ^ 1][i][2] = fmaf(d2, scale, xi2);
        }
        __syncthreads();
    }

    if (tid < 32) {   // TSTEPS even -> final state in buffer 0
        float* xo = Xout + ((long)b * 32 + tid) * 3;
        xo[0] = Xb[0][tid][0];
        xo[1] = Xb[0][tid][1];
        xo[2] = Xb[0][tid][2];
    }
}

extern "C" void kernel_launch(void* const* d_in, const int* in_sizes, int n_in,
                              void* d_out, int out_size, void* d_ws, size_t ws_size,
                              hipStream_t stream) {
    const float* e      = (const float*)d_in[0];
    const float* W1     = (const float*)d_in[1];
    const float* b1     = (const float*)d_in[2];
    const float* W2     = (const float*)d_in[3];
    const float* b2     = (const float*)d_in[4];
    const float* noise  = (const float*)d_in[5];
    const float* u_init = (const float*)d_in[6];
    float* out = (float*)d_out;

    unsigned short* Wpk = (unsigned short*)d_ws;   // 64 KB packed W1 hi/lo fragments

    float* r0 = out;             // D region, used first as raw ch0
    float* r1 = out + 524288;    // W region, used first as raw ch1
    float* X  = out + 1048576;   // X_pred region

    hipLaunchKernelGGL(kprep_w, dim3(16),   dim3(256), 0, stream, W1, Wpk);
    hipLaunchKernelGGL(k1_mlp,  dim3(8192), dim3(128), 0, stream, e, Wpk, b1, W2, b2, r0, r1);
    hipLaunchKernelGGL(k2_sym,  dim3(1056), dim3(256), 0, stream, r0, r1);
    hipLaunchKernelGGL(k3_solve, dim3(512), dim3(128), 0, stream, r0, r1, noise, u_init, X);
}

// Round 6
// 192.762 us; speedup vs baseline: 3.6596x; 1.1046x over previous
//
#include <hip/hip_runtime.h>
#include <math.h>

#define B_    512
#define N_    32
#define H_    128
#define KRANK 3
#define PSTEPS 10
#define TSTEPS 100

typedef __attribute__((ext_vector_type(4))) float f32x4;
typedef __attribute__((ext_vector_type(8))) short bf16x8;
typedef __attribute__((ext_vector_type(4))) unsigned short u16x4;

__device__ __forceinline__ unsigned short bf16_rne(float x) {
    unsigned int u = __float_as_uint(x);
    u += 0x7FFFu + ((u >> 16) & 1u);
    return (unsigned short)(u >> 16);
}

// tanh for x >= 0 via hardware exp/rcp: 1 - 2/(e^{2x}+1)
__device__ __forceinline__ float tanh_pos_fast(float x) {
    float e = __expf(2.f * x);
    return 1.f - 2.f * __builtin_amdgcn_rcpf(e + 1.f);
}

// ---------------- kprep: pack W1 hi/lo into per-lane MFMA B-fragment order ----------------
__global__ void kprep_w(const float* __restrict__ W1, unsigned short* __restrict__ Wpk) {
    int t = blockIdx.x * 256 + threadIdx.x;   // 4096 threads
    int lane = t & 63, nf = (t >> 6) & 7, bk = t >> 9;
    int n = nf * 16 + (lane & 15);
    int kbase = (bk & 3) * 32 + (lane >> 4) * 8;
    u16x4 o0, o1;
    #pragma unroll
    for (int i = 0; i < 8; ++i) {
        float w = W1[(kbase + i) * H_ + n];
        unsigned short hi = bf16_rne(w);
        unsigned short v;
        if (bk < 4) v = hi;
        else        v = bf16_rne(w - __uint_as_float((unsigned int)hi << 16));
        if (i < 4) o0[i] = v; else o1[i - 4] = v;
    }
    u16x4* dst = (u16x4*)(Wpk + (long)t * 8);
    dst[0] = o0;
    dst[1] = o1;
}

// ---------------- K1: fused 2-layer MLP, LDS-free, per-wave 32-edge tile ----------------
// A (e-tile) hi/lo fragments built once in registers from direct coalesced global reads.
// B (Wpk) fragments loaded once each: phase 1 B-hi (used by A-hi AND A-lo), phase 2 B-lo (A-hi).
__global__ __launch_bounds__(256, 2) void k1_mlp(
    const float* __restrict__ e, const unsigned short* __restrict__ Wpk,
    const float* __restrict__ b1, const float* __restrict__ W2,
    const float* __restrict__ b2,
    float* __restrict__ r0, float* __restrict__ r1) {

    int tid = threadIdx.x;
    int w = tid >> 6, lane = tid & 63;
    int mrow = lane & 15, kq = lane >> 4;          // kq 0..3
    long ebase = ((long)blockIdx.x * 4 + w) * 32;  // this wave's 32-edge tile

    // ---- build A fragments (hi = truncation, lo = rne of residual) ----
    bf16x8 ahi[2][4], alo[2][4];
    #pragma unroll
    for (int mf = 0; mf < 2; ++mf) {
        #pragma unroll
        for (int kf = 0; kf < 4; ++kf) {
            const float* ap = e + (ebase + mf * 16 + mrow) * H_ + kf * 32 + kq * 8;
            f32x4 v0 = *(const f32x4*)ap;
            f32x4 v1 = *(const f32x4*)(ap + 4);
            bf16x8 h, l;
            #pragma unroll
            for (int q = 0; q < 4; ++q) {
                unsigned int u0 = __float_as_uint(v0[q]);
                h[q] = (short)(u0 >> 16);
                l[q] = (short)bf16_rne(v0[q] - __uint_as_float(u0 & 0xffff0000u));
                unsigned int u1 = __float_as_uint(v1[q]);
                h[q + 4] = (short)(u1 >> 16);
                l[q + 4] = (short)bf16_rne(v1[q] - __uint_as_float(u1 & 0xffff0000u));
            }
            ahi[mf][kf] = h;
            alo[mf][kf] = l;
        }
    }

    // ---- init accumulators with b1 ----
    f32x4 acc[2][8];
    #pragma unroll
    for (int nf = 0; nf < 8; ++nf) {
        float bv = b1[nf * 16 + mrow];
        acc[0][nf] = (f32x4){bv, bv, bv, bv};
        acc[1][nf] = acc[0][nf];
    }

    // ---- phase 1: B-hi blocks, consumed by A-hi and A-lo ----
    #pragma unroll
    for (int kf = 0; kf < 4; ++kf) {
        bf16x8 bh[8];
        #pragma unroll
        for (int nf = 0; nf < 8; ++nf)
            bh[nf] = *(const bf16x8*)(Wpk + (((kf * 8 + nf) * 64 + lane) * 8));
        #pragma unroll
        for (int mf = 0; mf < 2; ++mf)
            #pragma unroll
            for (int nf = 0; nf < 8; ++nf)
                acc[mf][nf] = __builtin_amdgcn_mfma_f32_16x16x32_bf16(
                    ahi[mf][kf], bh[nf], acc[mf][nf], 0, 0, 0);
        #pragma unroll
        for (int mf = 0; mf < 2; ++mf)
            #pragma unroll
            for (int nf = 0; nf < 8; ++nf)
                acc[mf][nf] = __builtin_amdgcn_mfma_f32_16x16x32_bf16(
                    alo[mf][kf], bh[nf], acc[mf][nf], 0, 0, 0);
    }
    // ---- phase 2: B-lo blocks, consumed by A-hi ----
    #pragma unroll
    for (int kf = 0; kf < 4; ++kf) {
        bf16x8 bl[8];
        #pragma unroll
        for (int nf = 0; nf < 8; ++nf)
            bl[nf] = *(const bf16x8*)(Wpk + ((((4 + kf) * 8 + nf) * 64 + lane) * 8));
        #pragma unroll
        for (int mf = 0; mf < 2; ++mf)
            #pragma unroll
            for (int nf = 0; nf < 8; ++nf)
                acc[mf][nf] = __builtin_amdgcn_mfma_f32_16x16x32_bf16(
                    ahi[mf][kf], bl[nf], acc[mf][nf], 0, 0, 0);
    }

    // ---- layer 2 epilogue: relu, W2, 16-lane reduce, store ----
    float w2a[8], w2b[8];
    #pragma unroll
    for (int nf = 0; nf < 8; ++nf) {
        int j = nf * 16 + mrow;
        w2a[nf] = W2[j * 2];
        w2b[nf] = W2[j * 2 + 1];
    }
    float bb0 = b2[0], bb1 = b2[1];
    #pragma unroll
    for (int mf = 0; mf < 2; ++mf) {
        #pragma unroll
        for (int r = 0; r < 4; ++r) {
            float p0 = 0.f, p1 = 0.f;
            #pragma unroll
            for (int nf = 0; nf < 8; ++nf) {
                float hv = fmaxf(acc[mf][nf][r], 0.f);
                p0 = fmaf(hv, w2a[nf], p0);
                p1 = fmaf(hv, w2b[nf], p1);
            }
            #pragma unroll
            for (int d = 1; d < 16; d <<= 1) {
                p0 += __shfl_xor(p0, d);
                p1 += __shfl_xor(p1, d);
            }
            if (mrow == 0) {
                long edge = ebase + mf * 16 + kq * 4 + r;
                r0[edge] = p0 + bb0;
                r1[edge] = p1 + bb1;
            }
        }
    }
}

// ---------------- K2: symmetrize + softplus, in place over pairs (i<=j) ----------------
__device__ __forceinline__ float softplusf(float x) {
    return x > 20.f ? x : log1pf(expf(x));
}

__global__ void k2_sym(float* __restrict__ r0, float* __restrict__ r1) {
    int t = blockIdx.x * 256 + threadIdx.x;    // 512 * 528 = 270336 pairs
    int b = t / 528, r = t % 528;
    float disc = sqrtf((float)(4225 - 8 * r));
    int i = (int)((65.f - disc) * 0.5f);
    int j = r - (i * (65 - i)) / 2 + i;
    int base = b * 1024;
    int ij = base + i * 32 + j;
    int ji = base + j * 32 + i;
    float s0 = r0[ij] + r0[ji];
    float s1 = r1[ij] + r1[ji];
    float Dv = (i == j) ? 0.f : softplusf(s0);
    float Wv = softplusf(s1);
    r0[ij] = Dv; r0[ji] = Dv;
    r1[ij] = Wv; r1[ji] = Wv;
}

// ---------------- K3: 2 waves per batch, ping-pong X, fast-math chain ----------------
__global__ __launch_bounds__(128) void k3_solve(
    const float* __restrict__ Dg, const float* __restrict__ Wg,
    const float* __restrict__ noise, const float* __restrict__ u_init,
    float* __restrict__ Xout) {
    int b = blockIdx.x;
    int tid = threadIdx.x;          // 0..127

    __shared__ float Ds[32][33];
    __shared__ float Ws_[32][33];
    __shared__ float Gs[32][33];
    __shared__ float Xb[2][32][5];

    const float* Db = Dg + b * 1024;
    const float* Wb = Wg + b * 1024;
    #pragma unroll 1
    for (int s = 0; s < 8; ++s) {
        int idx = s * 128 + tid;
        int i = idx >> 5, j = idx & 31;
        Ds[i][j]  = Db[idx];
        Ws_[i][j] = Wb[idx];
    }
    __syncthreads();

    // G = D^T D
    #pragma unroll 1
    for (int s = 0; s < 8; ++s) {
        int idx = s * 128 + tid;
        int i = idx >> 5, j = idx & 31;
        float acc = 0.f;
        #pragma unroll
        for (int k = 0; k < 32; ++k) acc = fmaf(Ds[k][i], Ds[k][j], acc);
        Gs[i][j] = acc;
    }
    __syncthreads();

    int w = tid >> 6, lane = tid & 63;
    int il = lane & 15;
    int i = w * 16 + il;
    int jq = lane >> 4;
    float Drow[8], Wrow[8];
    #pragma unroll
    for (int jj = 0; jj < 8; ++jj) {
        int j = jq * 8 + jj;
        Drow[jj] = Ds[i][j];
        Wrow[jj] = Ws_[i][j];
    }

    if (tid < 32) {
        int l = tid;
        float Arow[32];
        #pragma unroll
        for (int j = 0; j < 32; ++j) Arow[j] = Gs[l][j];
        float x0 = 0.f, x1 = 0.f, x2 = 0.f;
        for (int s = 0; s < KRANK; ++s) {
            float u = u_init[((long)s * B_ + b) * 32 + l];
            for (int p = 0; p < PSTEPS; ++p) {
                float red = u * u;
                #pragma unroll
                for (int m = 1; m < 32; m <<= 1) red += __shfl_xor(red, m, 32);
                float un = u * __builtin_amdgcn_rcpf(fmaxf(__builtin_amdgcn_sqrtf(red), 1e-3f));
                float acc = 0.f;
                #pragma unroll
                for (int j = 0; j < 32; ++j) acc = fmaf(Arow[j], __shfl(un, j, 32), acc);
                u = acc;
            }
            float red = u * u;
            #pragma unroll
            for (int m = 1; m < 32; m <<= 1) red += __shfl_xor(red, m, 32);
            float sc = __builtin_amdgcn_sqrtf(__builtin_amdgcn_sqrtf(red + 0.01f));
            u *= sc;
            if (s == 0) x0 = u; else if (s == 1) x1 = u; else x2 = u;
            #pragma unroll
            for (int j = 0; j < 32; ++j) Arow[j] = fmaf(-u, __shfl(u, j, 32), Arow[j]);
        }
        const float* nb = noise + ((long)b * 32 + l) * 3;
        Xb[0][l][0] = x0 + nb[0];
        Xb[0][l][1] = x1 + nb[1];
        Xb[0][l][2] = x2 + nb[2];
    }
    __syncthreads();

    #pragma unroll 1
    for (int t = 0; t < TSTEPS; ++t) {
        int rb = t & 1;
        float a_t = 0.1f + 4.9f * (float)(TSTEPS - t) / (float)TSTEPS;
        float ra  = __builtin_amdgcn_rcpf(a_t);
        float xi0 = Xb[rb][i][0], xi1 = Xb[rb][i][1], xi2 = Xb[rb][i][2];
        float sc_ = 0.f, s0 = 0.f, s1 = 0.f, s2 = 0.f;
        #pragma unroll
        for (int jj = 0; jj < 8; ++jj) {
            int j = jq * 8 + jj;
            float xj0 = Xb[rb][j][0], xj1 = Xb[rb][j][1], xj2 = Xb[rb][j][2];
            float dx = xi0 - xj0, dy = xi1 - xj1, dz = xi2 - xj2;
            float dd = fmaf(dx, dx, fmaf(dy, dy, fmaf(dz, dz, 0.01f)));
            float c = -4.f * Wrow[jj] * fmaf(Drow[jj], __builtin_amdgcn_rsqf(dd), -1.f);
            sc_ += c;
            s0 = fmaf(c, xj0, s0);
            s1 = fmaf(c, xj1, s1);
            s2 = fmaf(c, xj2, s2);
        }
        sc_ += __shfl_xor(sc_, 16); s0 += __shfl_xor(s0, 16);
        s1  += __shfl_xor(s1, 16);  s2 += __shfl_xor(s2, 16);
        sc_ += __shfl_xor(sc_, 32); s0 += __shfl_xor(s0, 32);
        s1  += __shfl_xor(s1, 32);  s2 += __shfl_xor(s2, 32);
        if (jq == 0) {
            float d0 = -0.1f * fmaf(xi0, sc_, -s0);
            float d1 = -0.1f * fmaf(xi1, sc_, -s1);
            float d2 = -0.1f * fmaf(xi2, sc_, -s2);
            float sd = fmaf(d0, d0, fmaf(d1, d1, fmaf(d2, d2, 1e-3f)));
            float rs = __builtin_amdgcn_rsqf(sd);
            float arg = sd * rs * ra;
            float scale = a_t * tanh_pos_fast(arg) * rs;
            Xb[rb ^ 1][i][0] = fmaf(d0, scale, xi0);
            Xb[rb ^ 1][i][1] = fmaf(d1, scale, xi1);
            Xb[rb ^ 1][i][2] = fmaf(d2, scale, xi2);
        }
        __syncthreads();
    }

    if (tid < 32) {
        float* xo = Xout + ((long)b * 32 + tid) * 3;
        xo[0] = Xb[0][tid][0];
        xo[1] = Xb[0][tid][1];
        xo[2] = Xb[0][tid][2];
    }
}

extern "C" void kernel_launch(void* const* d_in, const int* in_sizes, int n_in,
                              void* d_out, int out_size, void* d_ws, size_t ws_size,
                              hipStream_t stream) {
    const float* e      = (const float*)d_in[0];
    const float* W1     = (const float*)d_in[1];
    const float* b1     = (const float*)d_in[2];
    const float* W2     = (const float*)d_in[3];
    const float* b2     = (const float*)d_in[4];
    const float* noise  = (const float*)d_in[5];
    const float* u_init = (const float*)d_in[6];
    float* out = (float*)d_out;

    unsigned short* Wpk = (unsigned short*)d_ws;   // 64 KB packed W1 hi/lo fragments

    float* r0 = out;             // D region, used first as raw ch0
    float* r1 = out + 524288;    // W region, used first as raw ch1
    float* X  = out + 1048576;   // X_pred region

    hipLaunchKernelGGL(kprep_w, dim3(16),   dim3(256), 0, stream, W1, Wpk);
    hipLaunchKernelGGL(k1_mlp,  dim3(4096), dim3(256), 0, stream, e, Wpk, b1, W2, b2, r0, r1);
    hipLaunchKernelGGL(k2_sym,  dim3(1056), dim3(256), 0, stream, r0, r1);
    hipLaunchKernelGGL(k3_solve, dim3(512), dim3(128), 0, stream, r0, r1, noise, u_init, X);
}